// Round 5
// baseline (292.193 us; speedup 1.0000x reference)
//
#include <hip/hip_runtime.h>
#include <hip/hip_cooperative_groups.h>
#include <math.h>

namespace cg = cooperative_groups;

#define B 8
#define S 4096
#define H 2048
#define LSYM 8
#define EMB 64
#define SPLIT 128
#define CHUNK (S / SPLIT)

// ---------------- Kernel 1: partial pooling over S, fully contiguous ----------------
__global__ __launch_bounds__(256) void pool_partial(const float* __restrict__ hid,
                                                    float* __restrict__ part) {
    const int sp = blockIdx.x;
    const int b  = blockIdx.y;
    const int t  = threadIdx.x;
    const float* slab = hid + (size_t)b * S * H + (size_t)sp * CHUNK * H;
    const int iters = CHUNK * (H / 1024);   // 64
    float4 a0 = {0.f, 0.f, 0.f, 0.f};
    float4 a1 = {0.f, 0.f, 0.f, 0.f};
    for (int i = 0; i < iters; i += 2) {
        const float4 v0 = *reinterpret_cast<const float4*>(slab + (size_t)i * 1024 + t * 4);
        const float4 v1 = *reinterpret_cast<const float4*>(slab + (size_t)(i + 1) * 1024 + t * 4);
        a0.x += v0.x; a0.y += v0.y; a0.z += v0.z; a0.w += v0.w;
        a1.x += v1.x; a1.y += v1.y; a1.z += v1.z; a1.w += v1.w;
    }
    float* dst = part + ((size_t)sp * B + b) * H;
    *reinterpret_cast<float4*>(dst + t * 4)        = a0;
    *reinterpret_cast<float4*>(dst + 1024 + t * 4) = a1;
}

// ---------------- Kernel 2: fused MLP pipeline (cooperative, 256 blocks) ----------------
struct MlpParams {
    const float* part; const float* gu;
    const float* ew1; const float* eb1;
    const float* g1;  const float* bb1;
    const float* ew2; const float* eb2;
    const float* emb_tab;
    const float* dw1; const float* db1;
    const float* g2;  const float* bb2;
    const float* dw2; const float* db2;
    float* pooled; float* out1; float* hs2; float* dec_sc;
};

__device__ __forceinline__ float block_sum256(float x, float* red) {
    const int t = threadIdx.x;
    red[t] = x;
    __syncthreads();
    for (int s = 128; s > 0; s >>= 1) {
        if (t < s) red[t] += red[t + s];
        __syncthreads();
    }
    const float r = red[0];
    __syncthreads();
    return r;
}

__global__ __launch_bounds__(256) void mlp_coop(MlpParams p) {
    cg::grid_group grid = cg::this_grid();
    __shared__ float red[256];
    __shared__ float hsm[256];
    __shared__ float es[LSYM * EMB];

    const int bid  = blockIdx.x;
    const int t    = threadIdx.x;
    const int gtid = bid * 256 + t;
    const int wv   = gtid >> 6;        // 0..1023
    const int lane = t & 63;

    // ---- phase 1: reduce partials -> pooled mean (4096 float4 outputs)
    if (gtid < B * H / 4) {
        const float4* pp = reinterpret_cast<const float4*>(p.part);
        float4 acc = {0.f, 0.f, 0.f, 0.f};
        for (int sp = 0; sp < SPLIT; ++sp) {
            const float4 v = pp[(size_t)sp * (B * H / 4) + gtid];
            acc.x += v.x; acc.y += v.y; acc.z += v.z; acc.w += v.w;
        }
        const float inv = 1.0f / (float)S;
        acc.x *= inv; acc.y *= inv; acc.z *= inv; acc.w *= inv;
        reinterpret_cast<float4*>(p.pooled)[gtid] = acc;
    }
    grid.sync();

    // ---- phase 2: enc1 — each wave computes 2 of the B*256 = 2048 outputs
#pragma unroll
    for (int k = 0; k < 2; ++k) {
        const int o  = wv * 2 + k;
        const int b  = o >> 8, tt = o & 255;
        const float4* wrow = reinterpret_cast<const float4*>(p.ew1 + (size_t)tt * H);
        const float4* prow = reinterpret_cast<const float4*>(p.pooled + b * H);
        float acc = 0.f;
#pragma unroll
        for (int i = 0; i < 8; ++i) {
            const float4 w = wrow[lane + 64 * i];
            const float4 v = prow[lane + 64 * i];
            acc += w.x * v.x + w.y * v.y + w.z * v.z + w.w * v.w;
        }
        for (int off = 32; off; off >>= 1) acc += __shfl_xor(acc, off, 64);
        if (lane == 0) p.out1[o] = acc + p.eb1[tt];
    }
    grid.sync();

    // ---- phase 3: middle chain — blocks 0..7, one per batch
    if (bid < B) {
        const int b = bid;
        float acc = p.out1[b * 256 + t];
        {   // LN1 + exact GELU
            const float m = block_sum256(acc, red) * (1.0f / 256.0f);
            const float d = acc - m;
            const float v = block_sum256(d * d, red) * (1.0f / 256.0f);
            float x = d * rsqrtf(v + 1e-5f) * p.g1[t] + p.bb1[t];
            x = 0.5f * x * (1.0f + erff(x * 0.70710678118654752f));
            hsm[t] = x;
        }
        __syncthreads();

        float z;
        {   // enc2 + gumbel
            float a2 = p.eb2[t];
            const float* w2row = p.ew2 + t * 256;
            for (int k = 0; k < 256; k += 4) {
                const float4 w = *reinterpret_cast<const float4*>(w2row + k);
                a2 += w.x * hsm[k] + w.y * hsm[k + 1] + w.z * hsm[k + 2] + w.w * hsm[k + 3];
            }
            const float u = p.gu[b * 256 + t];
            z = a2 - logf(-logf(u));
        }
        {   // per-l argmax over V=32 (first-max tiebreak) + embedding gather
            int   bi = t & 31;
            float bz = z;
            for (int off = 16; off; off >>= 1) {
                const float oz = __shfl_xor(bz, off, 32);
                const int   oi = __shfl_xor(bi, off, 32);
                if (oz > bz || (oz == bz && oi < bi)) { bz = oz; bi = oi; }
            }
            const int l = t >> 5, v32 = t & 31;
            es[l * EMB + v32]      = p.emb_tab[bi * EMB + v32];
            es[l * EMB + 32 + v32] = p.emb_tab[bi * EMB + 32 + v32];
        }
        __syncthreads();

        float a3 = p.db1[t];
        {   // dec1
            const float* d1row = p.dw1 + t * (LSYM * EMB);
            for (int k = 0; k < LSYM * EMB; k += 4) {
                const float4 w = *reinterpret_cast<const float4*>(d1row + k);
                a3 += w.x * es[k] + w.y * es[k + 1] + w.z * es[k + 2] + w.w * es[k + 3];
            }
        }
        {   // LN2 + exact GELU -> hs2
            const float m2 = block_sum256(a3, red) * (1.0f / 256.0f);
            const float dd = a3 - m2;
            const float vv = block_sum256(dd * dd, red) * (1.0f / 256.0f);
            float y = dd * rsqrtf(vv + 1e-5f) * p.g2[t] + p.bb2[t];
            y = 0.5f * y * (1.0f + erff(y * 0.70710678118654752f));
            p.hs2[b * 256 + t] = y;
        }
    }
    grid.sync();

    // ---- phase 4: dec2 — each wave computes 16 of the B*2048 outputs (same b per wave)
    {
        const int base = wv * 16;
        const int b    = base >> 11;
        const float4 h = reinterpret_cast<const float4*>(p.hs2 + b * 256)[lane];
#pragma unroll
        for (int k = 0; k < 16; ++k) {
            const int o = base + k, j = o & 2047;
            const float4 w = reinterpret_cast<const float4*>(p.dw2 + (size_t)j * 256)[lane];
            float acc = w.x * h.x + w.y * h.y + w.z * h.z + w.w * h.w;
            for (int off = 32; off; off >>= 1) acc += __shfl_xor(acc, off, 64);
            if (lane == 0) p.dec_sc[o] = 0.1f * (acc + p.db2[j]);
        }
    }
}

// ---------------- Kernel 3: residual broadcast add (dv hoisted, static indexing) ----------------
__global__ __launch_bounds__(256) void residual_add(const float* __restrict__ hid,
                                                    const float* __restrict__ dec,
                                                    float* __restrict__ out) {
    const size_t tid0 = (size_t)blockIdx.x * 256 + threadIdx.x;   // < 2^19
    const int h4 = (int)(tid0 & (H / 4 - 1));
    const float4* __restrict__ hv4 = reinterpret_cast<const float4*>(hid);
    const float4* __restrict__ dv4 = reinterpret_cast<const float4*>(dec);
    float4* __restrict__ ov4 = reinterpret_cast<float4*>(out);
    size_t i = tid0;
#pragma unroll
    for (int b = 0; b < B; ++b) {
        const float4 dv = dv4[b * (H / 4) + h4];
#pragma unroll
        for (int r = 0; r < 4; ++r, i += (size_t)1 << 19) {
            const float4 hv = hv4[i];
            float4 o;
            o.x = hv.x + dv.x; o.y = hv.y + dv.y; o.z = hv.z + dv.z; o.w = hv.w + dv.w;
            ov4[i] = o;
        }
    }
}

extern "C" void kernel_launch(void* const* d_in, const int* in_sizes, int n_in,
                              void* d_out, int out_size, void* d_ws, size_t ws_size,
                              hipStream_t stream) {
    const float* hid = (const float*)d_in[0];
    float* out = (float*)d_out;

    // workspace: [ part: SPLIT*B*H | pooled: B*H | dec_sc: B*H | out1: B*256 | hs2: B*256 ]
    float* part   = (float*)d_ws;
    float* pooled = part + (size_t)SPLIT * B * H;
    float* dec_sc = pooled + (size_t)B * H;
    float* out1   = dec_sc + (size_t)B * H;
    float* hs2    = out1 + (size_t)B * 256;

    pool_partial<<<dim3(SPLIT, B), 256, 0, stream>>>(hid, part);

    MlpParams mp;
    mp.part = part;
    mp.gu   = (const float*)d_in[1];
    mp.ew1  = (const float*)d_in[2];
    mp.eb1  = (const float*)d_in[3];
    mp.g1   = (const float*)d_in[4];
    mp.bb1  = (const float*)d_in[5];
    mp.ew2  = (const float*)d_in[6];
    mp.eb2  = (const float*)d_in[7];
    mp.emb_tab = (const float*)d_in[8];
    mp.dw1  = (const float*)d_in[9];
    mp.db1  = (const float*)d_in[10];
    mp.g2   = (const float*)d_in[11];
    mp.bb2  = (const float*)d_in[12];
    mp.dw2  = (const float*)d_in[13];
    mp.db2  = (const float*)d_in[14];
    mp.pooled = pooled; mp.out1 = out1; mp.hs2 = hs2; mp.dec_sc = dec_sc;

    void* kargs[] = { (void*)&mp };
    hipLaunchCooperativeKernel((const void*)mlp_coop, dim3(256), dim3(256), kargs, 0, stream);

    residual_add<<<2048, 256, 0, stream>>>(hid, dec_sc, out);
}

// Round 6
// 211.275 us; speedup vs baseline: 1.3830x; 1.3830x over previous
//
#include <hip/hip_runtime.h>
#include <math.h>

#define B 8
#define S 4096
#define H 2048
#define LSYM 8
#define EMB 64
#define SPLIT 128
#define CHUNK (S / SPLIT)

// ---------------- Kernel 1: partial pooling over S, contiguous slabs, 4 acc chains ----------------
__global__ __launch_bounds__(256) void pool_partial(const float* __restrict__ hid,
                                                    float* __restrict__ part) {
    const int sp = blockIdx.x;
    const int b  = blockIdx.y;
    const int t  = threadIdx.x;
    const float* slab = hid + (size_t)b * S * H + (size_t)sp * CHUNK * H;
    const int iters = CHUNK * (H / 1024);   // 64
    float4 a0 = {0.f, 0.f, 0.f, 0.f};
    float4 a1 = {0.f, 0.f, 0.f, 0.f};
    float4 a2 = {0.f, 0.f, 0.f, 0.f};
    float4 a3 = {0.f, 0.f, 0.f, 0.f};
#pragma unroll 4
    for (int i = 0; i < iters; i += 4) {
        const float4 v0 = *reinterpret_cast<const float4*>(slab + (size_t)i * 1024 + t * 4);
        const float4 v1 = *reinterpret_cast<const float4*>(slab + (size_t)(i + 1) * 1024 + t * 4);
        const float4 v2 = *reinterpret_cast<const float4*>(slab + (size_t)(i + 2) * 1024 + t * 4);
        const float4 v3 = *reinterpret_cast<const float4*>(slab + (size_t)(i + 3) * 1024 + t * 4);
        a0.x += v0.x; a0.y += v0.y; a0.z += v0.z; a0.w += v0.w;
        a1.x += v1.x; a1.y += v1.y; a1.z += v1.z; a1.w += v1.w;
        a2.x += v2.x; a2.y += v2.y; a2.z += v2.z; a2.w += v2.w;
        a3.x += v3.x; a3.y += v3.y; a3.z += v3.z; a3.w += v3.w;
    }
    // even i -> h = t*4 ; odd i -> h = 1024 + t*4
    float4 e, o;
    e.x = a0.x + a2.x; e.y = a0.y + a2.y; e.z = a0.z + a2.z; e.w = a0.w + a2.w;
    o.x = a1.x + a3.x; o.y = a1.y + a3.y; o.z = a1.z + a3.z; o.w = a1.w + a3.w;
    float* dst = part + ((size_t)sp * B + b) * H;
    *reinterpret_cast<float4*>(dst + t * 4)        = e;
    *reinterpret_cast<float4*>(dst + 1024 + t * 4) = o;
}

// ---------------- Kernel 2: reduce partials -> pooled mean ----------------
__global__ __launch_bounds__(256) void pool_reduce(const float* __restrict__ part,
                                                   float* __restrict__ pooled) {
    const int i4 = blockIdx.x * 256 + threadIdx.x;
    if (i4 >= B * H / 4) return;
    float4 acc = {0.f, 0.f, 0.f, 0.f};
    for (int sp = 0; sp < SPLIT; ++sp) {
        const float4 v = *reinterpret_cast<const float4*>(part + (size_t)sp * B * H + (size_t)i4 * 4);
        acc.x += v.x; acc.y += v.y; acc.z += v.z; acc.w += v.w;
    }
    const float inv = 1.0f / (float)S;
    acc.x *= inv; acc.y *= inv; acc.z *= inv; acc.w *= inv;
    *reinterpret_cast<float4*>(pooled + (size_t)i4 * 4) = acc;
}

// ---------------- Kernel 3a: enc layer 1 matvec, one wave per output ----------------
__global__ __launch_bounds__(256) void enc1_matvec(const float* __restrict__ pooled,
                                                   const float* __restrict__ ew1,
                                                   const float* __restrict__ eb1,
                                                   float* __restrict__ out1) {
    const int wv   = (blockIdx.x * 256 + threadIdx.x) >> 6;
    const int lane = threadIdx.x & 63;
    const int b = wv >> 8, t = wv & 255;
    const float4* wrow = reinterpret_cast<const float4*>(ew1 + (size_t)t * H);
    const float4* prow = reinterpret_cast<const float4*>(pooled + b * H);
    float acc = 0.f;
#pragma unroll
    for (int i = 0; i < 8; ++i) {
        const float4 w = wrow[lane + 64 * i];
        const float4 p = prow[lane + 64 * i];
        acc += w.x * p.x + w.y * p.y + w.z * p.z + w.w * p.w;
    }
    for (int off = 32; off; off >>= 1) acc += __shfl_xor(acc, off, 64);
    if (lane == 0) out1[b * 256 + t] = acc + eb1[t];
}

// ---------------- Kernel 3b: middle chain ----------------
__device__ __forceinline__ float block_sum256(float x, float* red) {
    const int t = threadIdx.x;
    red[t] = x;
    __syncthreads();
    for (int s = 128; s > 0; s >>= 1) {
        if (t < s) red[t] += red[t + s];
        __syncthreads();
    }
    const float r = red[0];
    __syncthreads();
    return r;
}

__global__ __launch_bounds__(256) void mlp_middle(
    const float* __restrict__ out1, const float* __restrict__ gu,
    const float* __restrict__ g1,  const float* __restrict__ bb1,
    const float* __restrict__ ew2, const float* __restrict__ eb2,
    const float* __restrict__ emb_tab,
    const float* __restrict__ dw1, const float* __restrict__ db1,
    const float* __restrict__ g2,  const float* __restrict__ bb2,
    float* __restrict__ hs2) {
    __shared__ float red[256];
    __shared__ float hs[256];
    __shared__ float es[LSYM * EMB];

    const int b = blockIdx.x;
    const int t = threadIdx.x;

    float acc = out1[b * 256 + t];
    {
        const float m = block_sum256(acc, red) * (1.0f / 256.0f);
        const float d = acc - m;
        const float v = block_sum256(d * d, red) * (1.0f / 256.0f);
        float x = d * rsqrtf(v + 1e-5f) * g1[t] + bb1[t];
        x = 0.5f * x * (1.0f + erff(x * 0.70710678118654752f));
        hs[t] = x;
    }
    __syncthreads();

    float z;
    {
        float a2 = eb2[t];
        const float* w2row = ew2 + t * 256;
        for (int k = 0; k < 256; k += 4) {
            const float4 w = *reinterpret_cast<const float4*>(w2row + k);
            a2 += w.x * hs[k] + w.y * hs[k + 1] + w.z * hs[k + 2] + w.w * hs[k + 3];
        }
        const float u = gu[b * 256 + t];
        z = a2 - logf(-logf(u));
    }

    {
        int   bi = t & 31;
        float bz = z;
        for (int off = 16; off; off >>= 1) {
            const float oz = __shfl_xor(bz, off, 32);
            const int   oi = __shfl_xor(bi, off, 32);
            if (oz > bz || (oz == bz && oi < bi)) { bz = oz; bi = oi; }
        }
        const int l = t >> 5, v32 = t & 31;
        es[l * EMB + v32]      = emb_tab[bi * EMB + v32];
        es[l * EMB + 32 + v32] = emb_tab[bi * EMB + 32 + v32];
    }
    __syncthreads();

    float a3 = db1[t];
    {
        const float* d1row = dw1 + t * (LSYM * EMB);
        for (int k = 0; k < LSYM * EMB; k += 4) {
            const float4 w = *reinterpret_cast<const float4*>(d1row + k);
            a3 += w.x * es[k] + w.y * es[k + 1] + w.z * es[k + 2] + w.w * es[k + 3];
        }
    }
    {
        const float m2 = block_sum256(a3, red) * (1.0f / 256.0f);
        const float dd = a3 - m2;
        const float vv = block_sum256(dd * dd, red) * (1.0f / 256.0f);
        float y = dd * rsqrtf(vv + 1e-5f) * g2[t] + bb2[t];
        y = 0.5f * y * (1.0f + erff(y * 0.70710678118654752f));
        hs2[b * 256 + t] = y;
    }
}

// ---------------- Kernel 3c: dec layer 2 matvec, one wave per output ----------------
__global__ __launch_bounds__(256) void dec2_matvec(const float* __restrict__ hs2,
                                                   const float* __restrict__ dw2,
                                                   const float* __restrict__ db2,
                                                   float* __restrict__ dec_sc) {
    const int wv   = (blockIdx.x * 256 + threadIdx.x) >> 6;
    const int lane = threadIdx.x & 63;
    const int b = wv >> 11, j = wv & 2047;
    const float4 w = reinterpret_cast<const float4*>(dw2 + (size_t)j * 256)[lane];
    const float4 h = reinterpret_cast<const float4*>(hs2 + b * 256)[lane];
    float acc = w.x * h.x + w.y * h.y + w.z * h.z + w.w * h.w;
    for (int off = 32; off; off >>= 1) acc += __shfl_xor(acc, off, 64);
    if (lane == 0) dec_sc[b * 2048 + j] = 0.1f * (acc + db2[j]);
}

// ---------------- Kernel 4: residual broadcast add (dv hoisted, plain stores) ----------------
__global__ __launch_bounds__(256) void residual_add(const float* __restrict__ hid,
                                                    const float* __restrict__ dec,
                                                    float* __restrict__ out) {
    const size_t tid0 = (size_t)blockIdx.x * 256 + threadIdx.x;   // < 2^19
    const int h4 = (int)(tid0 & (H / 4 - 1));
    const float4* __restrict__ hv4 = reinterpret_cast<const float4*>(hid);
    const float4* __restrict__ dv4 = reinterpret_cast<const float4*>(dec);
    float4* __restrict__ ov4 = reinterpret_cast<float4*>(out);
    size_t i = tid0;
#pragma unroll
    for (int b = 0; b < B; ++b) {
        const float4 dv = dv4[b * (H / 4) + h4];
#pragma unroll
        for (int r = 0; r < 4; ++r, i += (size_t)1 << 19) {
            const float4 hv = hv4[i];
            float4 o;
            o.x = hv.x + dv.x; o.y = hv.y + dv.y; o.z = hv.z + dv.z; o.w = hv.w + dv.w;
            ov4[i] = o;
        }
    }
}

extern "C" void kernel_launch(void* const* d_in, const int* in_sizes, int n_in,
                              void* d_out, int out_size, void* d_ws, size_t ws_size,
                              hipStream_t stream) {
    const float* hid   = (const float*)d_in[0];
    const float* gu    = (const float*)d_in[1];
    const float* ew1   = (const float*)d_in[2];
    const float* eb1   = (const float*)d_in[3];
    const float* g1    = (const float*)d_in[4];
    const float* bb1   = (const float*)d_in[5];
    const float* ew2   = (const float*)d_in[6];
    const float* eb2   = (const float*)d_in[7];
    const float* emb   = (const float*)d_in[8];
    const float* dw1   = (const float*)d_in[9];
    const float* db1   = (const float*)d_in[10];
    const float* g2    = (const float*)d_in[11];
    const float* bb2   = (const float*)d_in[12];
    const float* dw2   = (const float*)d_in[13];
    const float* db2   = (const float*)d_in[14];
    float* out = (float*)d_out;

    // workspace: [ part: SPLIT*B*H | pooled: B*H | dec_sc: B*H | out1: B*256 | hs2: B*256 ]
    float* part   = (float*)d_ws;
    float* pooled = part + (size_t)SPLIT * B * H;
    float* dec_sc = pooled + (size_t)B * H;
    float* out1   = dec_sc + (size_t)B * H;
    float* hs2    = out1 + (size_t)B * 256;

    pool_partial<<<dim3(SPLIT, B), 256, 0, stream>>>(hid, part);
    pool_reduce<<<(B * H / 4 + 255) / 256, 256, 0, stream>>>(part, pooled);
    enc1_matvec<<<B * 256 / 4, 256, 0, stream>>>(pooled, ew1, eb1, out1);
    mlp_middle<<<B, 256, 0, stream>>>(out1, gu, g1, bb1, ew2, eb2, emb,
                                      dw1, db1, g2, bb2, hs2);
    dec2_matvec<<<B * 2048 / 4, 256, 0, stream>>>(hs2, dw2, db2, dec_sc);
    residual_add<<<2048, 256, 0, stream>>>(hid, dec_sc, out);
}